// Round 1
// baseline (166.310 us; speedup 1.0000x reference)
//
#include <hip/hip_runtime.h>

// ---------------------------------------------------------------------------
// GuidedAttentionL1Loss on MI355X
// out[0] = loss = nll + (ALPHA/2)*sum|params| + (BETA/2)*mean_b(sum_d2_b/L_b)
// out[1] = nll
// ---------------------------------------------------------------------------

constexpr int MAXL = 3072;          // max segment length by construction (2048 +/- 1024)
constexpr float INV_SQRT_2PI = 0.39894228040143267794f;

// acc layout in d_ws (doubles): [0]=sum|params|, [1]=sum nll terms, [2]=sum(sum_d2/L)
// starts array (ints) at byte offset 256.

__device__ __forceinline__ float block_reduce_f32(float v, float* s_tmp) {
#pragma unroll
    for (int off = 32; off > 0; off >>= 1) v += __shfl_down(v, off, 64);
    int lane = threadIdx.x & 63;
    int wv = threadIdx.x >> 6;
    __syncthreads();                 // protect s_tmp from previous call's readers
    if (lane == 0) s_tmp[wv] = v;
    __syncthreads();
    return s_tmp[0] + s_tmp[1] + s_tmp[2] + s_tmp[3];
}

// ---- exclusive scan of lengths -> starts (B <= 4096, single block) ----------
__global__ __launch_bounds__(1024) void scan_kernel(const int* __restrict__ lengths,
                                                    int* __restrict__ starts, int Bn) {
    __shared__ int s[1024];
    int tid = threadIdx.x;
    int base = tid * 4;
    int l0 = (base     < Bn) ? lengths[base]     : 0;
    int l1 = (base + 1 < Bn) ? lengths[base + 1] : 0;
    int l2 = (base + 2 < Bn) ? lengths[base + 2] : 0;
    int l3 = (base + 3 < Bn) ? lengths[base + 3] : 0;
    s[tid] = l0 + l1 + l2 + l3;
    __syncthreads();
#pragma unroll
    for (int off = 1; off < 1024; off <<= 1) {
        int v = (tid >= off) ? s[tid - off] : 0;
        __syncthreads();
        s[tid] += v;
        __syncthreads();
    }
    int excl = (tid == 0) ? 0 : s[tid - 1];
    if (base     < Bn) starts[base]     = excl;
    if (base + 1 < Bn) starts[base + 1] = excl + l0;
    if (base + 2 < Bn) starts[base + 2] = excl + l0 + l1;
    if (base + 3 < Bn) starts[base + 3] = excl + l0 + l1 + l2;
}

// ---- L1 penalty: sum |params| ----------------------------------------------
__global__ __launch_bounds__(256) void l1_kernel(const float* __restrict__ p, int n,
                                                 double* __restrict__ acc) {
    __shared__ float s_tmp[4];
    int n4 = n >> 2;
    const float4* p4 = (const float4*)p;
    float s = 0.f;
    int stride = gridDim.x * 256;
    for (int i = blockIdx.x * 256 + threadIdx.x; i < n4; i += stride) {
        float4 v = p4[i];
        s += fabsf(v.x) + fabsf(v.y) + fabsf(v.z) + fabsf(v.w);
    }
    // tail (n not multiple of 4)
    if (blockIdx.x == 0 && threadIdx.x == 0) {
        for (int i = n4 * 4; i < n; ++i) s += fabsf(p[i]);
    }
    float tot = block_reduce_f32(s, s_tmp);
    if (threadIdx.x == 0) atomicAdd(acc + 0, (double)tot);
}

// ---- NLL over B rows of 2 logits -------------------------------------------
__global__ __launch_bounds__(256) void nll_kernel(const float* __restrict__ logits,
                                                  const int* __restrict__ labels,
                                                  double* __restrict__ acc, int Bn) {
    __shared__ float s_tmp[4];
    int i = blockIdx.x * 256 + threadIdx.x;
    float v = 0.f;
    if (i < Bn) {
        float l0 = logits[2 * i], l1 = logits[2 * i + 1];
        float m = fmaxf(l0, l1);
        float lse = m + logf(expf(l0 - m) + expf(l1 - m));
        float sel = (labels[i] == 1) ? l1 : l0;
        v = lse - sel;                 // -log p(label)
    }
    float tot = block_reduce_f32(v, s_tmp);
    if (threadIdx.x == 0) atomicAdd(acc + 1, (double)tot);
}

// ---- per-segment guided attention penalty ----------------------------------
// One block per segment. y and r_hat staged in LDS; attn read from HBM once.
__global__ __launch_bounds__(256) void seg_kernel(const float* __restrict__ attn,
                                                  const int* __restrict__ labels,
                                                  const int* __restrict__ lengths,
                                                  const int* __restrict__ starts,
                                                  double* __restrict__ acc) {
    __shared__ float s_y[MAXL];
    __shared__ float s_r[MAXL];
    __shared__ float s_tmp[4];
    int b = blockIdx.x;
    int L = lengths[b];
    int start = starts[b];
    int tid = threadIdx.x;
    float invL = 1.0f / (float)L;
    bool fits = (L <= MAXL);          // always true for this problem's inputs

    // pass A: sum_y, sum_xy (stage y in LDS)
    float sum_y = 0.f, sum_xy = 0.f;
    for (int i = tid; i < L; i += 256) {
        float y = attn[start + i];
        if (fits) s_y[i] = y;
        float x = (float)(i + 1) * invL;
        sum_y += y;
        sum_xy = fmaf(x, y, sum_xy);
    }
    float tot_y  = block_reduce_f32(sum_y, s_tmp);
    float tot_xy = block_reduce_f32(sum_xy, s_tmp);
    float mean = tot_xy / tot_y;

    int label = labels[b];
    float ideal_std = ((label == 1) ? 1.0f : 1000.0f) * invL;
    float inv_std = 1.0f / ideal_std;
    float inv_norm = INV_SQRT_2PI * inv_std;   // 1/(std*sqrt(2pi))

    // pass B: r_hat and its segment sum (stage r_hat in LDS)
    float sum_rh = 0.f;
    for (int i = tid; i < L; i += 256) {
        float x = (float)(i + 1) * invL;
        float z = (x - mean) * inv_std;
        float rh = expf(-0.5f * z * z) * inv_norm;
        if (fits) s_r[i] = rh;
        sum_rh += rh;
    }
    float tot_rh = block_reduce_f32(sum_rh, s_tmp);
    float inv_den = 1.0f / (tot_rh + 1e-6f);

    // pass C: sum (y - r)^2
    float sum_d2 = 0.f;
    for (int i = tid; i < L; i += 256) {
        float y, rh;
        if (fits) {
            y = s_y[i];
            rh = s_r[i];
        } else {  // fallback (never taken for this input shape)
            y = attn[start + i];
            float x = (float)(i + 1) * invL;
            float z = (x - mean) * inv_std;
            rh = expf(-0.5f * z * z) * inv_norm;
        }
        float d = y - rh * inv_den;
        sum_d2 = fmaf(d, d, sum_d2);
    }
    float tot_d2 = block_reduce_f32(sum_d2, s_tmp);
    if (tid == 0) atomicAdd(acc + 2, (double)(tot_d2 * invL));
}

// ---- finalize ---------------------------------------------------------------
__global__ void finalize_kernel(const double* __restrict__ acc, float* __restrict__ out,
                                int Bn) {
    if (blockIdx.x == 0 && threadIdx.x == 0) {
        double nll = acc[1] / (double)Bn;
        double loss = nll + 5e-4 * acc[0] + 0.05 * (acc[2] / (double)Bn);
        out[0] = (float)loss;
        out[1] = (float)nll;
    }
}

extern "C" void kernel_launch(void* const* d_in, const int* in_sizes, int n_in,
                              void* d_out, int out_size, void* d_ws, size_t ws_size,
                              hipStream_t stream) {
    const float* logits = (const float*)d_in[0];
    const float* params = (const float*)d_in[1];
    const float* attn   = (const float*)d_in[2];
    const int*   labels = (const int*)d_in[3];
    const int*   lengths= (const int*)d_in[4];
    // d_in[5] (seg_ids) intentionally unused: starts recomputed from lengths.

    int Bn = in_sizes[3];           // number of bags
    int P  = in_sizes[1];           // param count

    double* acc   = (double*)d_ws;
    int*    starts= (int*)((char*)d_ws + 256);

    hipMemsetAsync(d_ws, 0, 64, stream);  // zero the three accumulators

    hipLaunchKernelGGL(scan_kernel, dim3(1), dim3(1024), 0, stream, lengths, starts, Bn);
    hipLaunchKernelGGL(l1_kernel, dim3(256), dim3(256), 0, stream, params, P, acc);
    hipLaunchKernelGGL(nll_kernel, dim3((Bn + 255) / 256), dim3(256), 0, stream,
                       logits, labels, acc, Bn);
    hipLaunchKernelGGL(seg_kernel, dim3(Bn), dim3(256), 0, stream,
                       attn, labels, lengths, starts, acc);
    hipLaunchKernelGGL(finalize_kernel, dim3(1), dim3(64), 0, stream,
                       acc, (float*)d_out, Bn);
}

// Round 2
// 139.962 us; speedup vs baseline: 1.1883x; 1.1883x over previous
//
#include <hip/hip_runtime.h>

// ---------------------------------------------------------------------------
// GuidedAttentionL1Loss on MI355X — R1
// loss = nll + (ALPHA/2)*sum|params| + (BETA/2)*mean_b( sum_b (y-r)^2 / L_b )
// Key changes vs R0: no atomics (f64 atomicAdd = CAS storm), wave-per-segment
// shuffle reduction (no barriers/LDS), analytic expansion removes pass C.
// ---------------------------------------------------------------------------

constexpr float INV_SQRT_2PI = 0.39894228040143267794f;

// ws layout:
//   [0]      int   starts[4096]
//   [16384]  float segout[4096]
//   [32768]  float l1part[256]
//   [33792]  float nllpart[16]

// ---- prep: blocks 0..255 = L1 partials, 256..(256+nbNll-1) = NLL partials,
//            last block = exclusive scan of lengths -> starts ----------------
__global__ __launch_bounds__(256) void prep_kernel(
    const float* __restrict__ logits, const float* __restrict__ params,
    const int* __restrict__ labels, const int* __restrict__ lengths,
    int P, int Bn, int nbNll,
    int* __restrict__ starts, float* __restrict__ l1part,
    float* __restrict__ nllpart) {
  __shared__ float s_tmp[4];
  __shared__ int s_wsum[4];
  int bid = blockIdx.x, tid = threadIdx.x;
  int lane = tid & 63, wv = tid >> 6;

  if (bid < 256) {
    // ---- L1: sum |params| ----
    const float4* p4 = (const float4*)params;
    int n4 = P >> 2;
    float s = 0.f;
    for (int i = bid * 256 + tid; i < n4; i += 256 * 256) {
      float4 v = p4[i];
      s += fabsf(v.x) + fabsf(v.y) + fabsf(v.z) + fabsf(v.w);
    }
    if (bid == 0 && tid == 0)
      for (int i = n4 << 2; i < P; ++i) s += fabsf(params[i]);
#pragma unroll
    for (int off = 32; off; off >>= 1) s += __shfl_down(s, off, 64);
    if (lane == 0) s_tmp[wv] = s;
    __syncthreads();
    if (tid == 0) l1part[bid] = s_tmp[0] + s_tmp[1] + s_tmp[2] + s_tmp[3];
  } else if (bid < 256 + nbNll) {
    // ---- NLL partials ----
    int r = (bid - 256) * 256 + tid;
    float v = 0.f;
    if (r < Bn) {
      float l0 = logits[2 * r], l1 = logits[2 * r + 1];
      float m = fmaxf(l0, l1);
      float lse = m + logf(expf(l0 - m) + expf(l1 - m));
      v = lse - ((labels[r] == 1) ? l1 : l0);
    }
#pragma unroll
    for (int off = 32; off; off >>= 1) v += __shfl_down(v, off, 64);
    if (lane == 0) s_tmp[wv] = v;
    __syncthreads();
    if (tid == 0) nllpart[bid - 256] = s_tmp[0] + s_tmp[1] + s_tmp[2] + s_tmp[3];
  } else {
    // ---- exclusive scan of lengths (Bn <= 4096): 16 per thread ----
    int base = tid * 16;
    int lv[16];
    int local = 0;
#pragma unroll
    for (int k = 0; k < 16; ++k) {
      int idx = base + k;
      lv[k] = (idx < Bn) ? lengths[idx] : 0;
      local += lv[k];
    }
    int v = local;
#pragma unroll
    for (int off = 1; off < 64; off <<= 1) {
      int t = __shfl_up(v, off, 64);
      if (lane >= off) v += t;
    }
    if (lane == 63) s_wsum[wv] = v;
    __syncthreads();
    int woff = 0;
    for (int w = 0; w < wv; ++w) woff += s_wsum[w];
    int excl = woff + v - local;  // exclusive prefix for this thread's chunk
#pragma unroll
    for (int k = 0; k < 16; ++k) {
      int idx = base + k;
      if (idx < Bn) { starts[idx] = excl; excl += lv[k]; }
    }
  }
}

// ---- per-segment penalty: ONE WAVE per segment, shuffle-only reductions ----
// sum(y-r)^2 = sum(y^2) - 2*sum(y*rh)/den + sum(rh^2)/den^2, den = sum(rh)+1e-6
__global__ __launch_bounds__(256) void seg_kernel(
    const float* __restrict__ attn, const int* __restrict__ labels,
    const int* __restrict__ lengths, const int* __restrict__ starts,
    float* __restrict__ segout, int Bn) {
  int wid = (blockIdx.x << 2) + (threadIdx.x >> 6);
  if (wid >= Bn) return;
  int lane = threadIdx.x & 63;
  int L = lengths[wid];
  const float* a = attn + starts[wid];
  float invL = 1.0f / (float)L;

  // pass A: sum_y, sum_xy, sum_y2 (single HBM read of the segment)
  float sy = 0.f, sxy = 0.f, syy = 0.f;
  for (int i = lane; i < L; i += 64) {
    float y = a[i];
    float x = (float)(i + 1) * invL;
    sy += y;
    sxy = fmaf(x, y, sxy);
    syy = fmaf(y, y, syy);
  }
#pragma unroll
  for (int off = 32; off; off >>= 1) {
    sy  += __shfl_xor(sy, off, 64);
    sxy += __shfl_xor(sxy, off, 64);
  }
  float mean = sxy / sy;
  float ideal_std = ((labels[wid] == 1) ? 1.0f : 1000.0f) * invL;
  float inv_std = 1.0f / ideal_std;
  float inv_norm = INV_SQRT_2PI * inv_std;

  // pass B: re-read y (L2/L3-hot), accumulate rh moments
  float sr = 0.f, syr = 0.f, srr = 0.f;
  for (int i = lane; i < L; i += 64) {
    float y = a[i];
    float x = (float)(i + 1) * invL;
    float z = (x - mean) * inv_std;
    float rh = expf(-0.5f * z * z) * inv_norm;
    sr  += rh;
    syr = fmaf(y, rh, syr);
    srr = fmaf(rh, rh, srr);
  }
#pragma unroll
  for (int off = 32; off; off >>= 1) {
    syy += __shfl_xor(syy, off, 64);
    sr  += __shfl_xor(sr, off, 64);
    syr += __shfl_xor(syr, off, 64);
    srr += __shfl_xor(srr, off, 64);
  }
  if (lane == 0) {
    float inv_den = 1.0f / (sr + 1e-6f);
    float d2 = syy - 2.0f * syr * inv_den + srr * inv_den * inv_den;
    segout[wid] = d2 * invL;
  }
}

// ---- finalize: f64 reduction of all partials, write [loss, nll] ------------
__global__ __launch_bounds__(1024) void finalize_kernel(
    const float* __restrict__ segout, const float* __restrict__ l1part,
    const float* __restrict__ nllpart, float* __restrict__ out, int Bn) {
  __shared__ double s_red[16][3];
  int tid = threadIdx.x, lane = tid & 63, wv = tid >> 6;
  double s_seg = 0.0, s_l1 = 0.0, s_nll = 0.0;
  for (int i = tid; i < Bn; i += 1024) s_seg += (double)segout[i];
  if (tid < 256) s_l1 = (double)l1part[tid];
  if (tid < 16) s_nll = (double)nllpart[tid];
#pragma unroll
  for (int off = 32; off; off >>= 1) {
    s_seg += __shfl_down(s_seg, off, 64);
    s_l1  += __shfl_down(s_l1, off, 64);
    s_nll += __shfl_down(s_nll, off, 64);
  }
  if (lane == 0) { s_red[wv][0] = s_seg; s_red[wv][1] = s_l1; s_red[wv][2] = s_nll; }
  __syncthreads();
  if (tid == 0) {
    double a = 0, b = 0, c = 0;
    for (int w = 0; w < 16; ++w) { a += s_red[w][0]; b += s_red[w][1]; c += s_red[w][2]; }
    double nll = c / (double)Bn;
    double loss = nll + 5e-4 * b + 0.05 * (a / (double)Bn);
    out[0] = (float)loss;
    out[1] = (float)nll;
  }
}

extern "C" void kernel_launch(void* const* d_in, const int* in_sizes, int n_in,
                              void* d_out, int out_size, void* d_ws, size_t ws_size,
                              hipStream_t stream) {
  const float* logits  = (const float*)d_in[0];
  const float* params  = (const float*)d_in[1];
  const float* attn    = (const float*)d_in[2];
  const int*   labels  = (const int*)d_in[3];
  const int*   lengths = (const int*)d_in[4];
  // d_in[5] (seg_ids) unused: starts recomputed from lengths.

  int Bn = in_sizes[3];
  int P  = in_sizes[1];

  int*   starts  = (int*)d_ws;
  float* segout  = (float*)((char*)d_ws + 16384);
  float* l1part  = (float*)((char*)d_ws + 32768);
  float* nllpart = (float*)((char*)d_ws + 33792);

  int nbNll = (Bn + 255) / 256;            // 16
  int grid1 = 256 + nbNll + 1;             // L1 blocks + NLL blocks + scan block

  hipLaunchKernelGGL(prep_kernel, dim3(grid1), dim3(256), 0, stream,
                     logits, params, labels, lengths, P, Bn, nbNll,
                     starts, l1part, nllpart);
  hipLaunchKernelGGL(seg_kernel, dim3((Bn + 3) / 4), dim3(256), 0, stream,
                     attn, labels, lengths, starts, segout, Bn);
  hipLaunchKernelGGL(finalize_kernel, dim3(1), dim3(1024), 0, stream,
                     segout, l1part, nllpart, (float*)d_out, Bn);
}